// Round 2
// baseline (1686.843 us; speedup 1.0000x reference)
//
#include <hip/hip_runtime.h>
#include <stdint.h>

// Binary-weight MLP forward, exact int8 digit-plane formulation.
// R5: hybrid pipeline. A digit-planes stream global->VGPR (2-deep ping-pong),
// B signs stream global->LDS via global_load_lds (3-deep). One barrier per
// KT=64 stage with counted s_waitcnt vmcnt(2) (issue order A-loads then
// B-DMA makes N constant). Removes the R4 LDS-bandwidth saturation: LDS
// now carries only B (32KB read + 16KB write per stage per CU vs 144KB).

typedef int v4i  __attribute__((ext_vector_type(4)));
typedef int v16i __attribute__((ext_vector_type(16)));

#define B_ROWS   16384
#define DIM      4096
#define MT       64      // block m-tile
#define NT       128     // block n-tile
#define KT       64      // k-tile (pipeline stage)

#define WS_LOGIT  0
#define WS_W2S    65536
#define WS_B      69632
#define WS_A      (69632 + 16777216)
#define WS_NEEDED ((size_t)WS_A + 268435456ULL)

__device__ __forceinline__ void dma16(const void* g, void* l) {
    __builtin_amdgcn_global_load_lds(
        (const __attribute__((address_space(1))) void*)g,
        (__attribute__((address_space(3))) void*)l, 16, 0, 0);
}

// ---------------- pack x -> fragment-ordered digit planes in wsA -----------
// Global layout: offA(m,k,d) = (m>>5)<<19 | (k>>5)<<12 | d<<10 | L<<4 | (k&15)
//   with L = ((k>>4)&1)*32 + (m&31)  (== MFMA A-operand lane index).
__global__ void pack_x_frag_kernel(const float* __restrict__ x, int8_t* __restrict__ wsA) {
    __shared__ __align__(16) int8_t tile[16384];
    const int mb32 = blockIdx.x, t = threadIdx.x;
    const int r = t >> 3;          // row within 32-row group
    const int c = t & 7;           // float4-column subgroup
    const int kh = (c >> 2) & 1;   // (k>>4)&1 for this thread's elements
    const int L = kh * 32 + r;
    const int ldsQ = L * 16 + (c & 3) * 4;   // + i*4096 + d*1024
    const float* srcRow = x + ((size_t)(mb32 * 32 + r) << 12);
    int8_t* dstBase = wsA + ((size_t)mb32 << 19);

    for (int kw = 0; kw < 32; ++kw) {
#pragma unroll
        for (int i = 0; i < 4; ++i) {
            const int j = c + 8 * i;                       // float4 index in window
            float4 f = ((const float4*)(srcRow + (kw << 7)))[j];
            float fv[4] = {f.x, f.y, f.z, f.w};
            int dig[4][4];                                  // [elem][digit]
#pragma unroll
            for (int e = 0; e < 4; ++e) {
                int v = __float2int_rn(fv[e] * 67108864.0f); // * 2^26, exact
#pragma unroll
                for (int d = 0; d < 4; ++d) {
                    int b = (int)(int8_t)(v & 0xff);
                    dig[e][d] = b & 0xff;
                    v = (v - b) >> 8;                        // exact
                }
            }
#pragma unroll
            for (int d = 0; d < 4; ++d) {
                uint32_t wrd = (uint32_t)dig[0][d] | ((uint32_t)dig[1][d] << 8)
                             | ((uint32_t)dig[2][d] << 16) | ((uint32_t)dig[3][d] << 24);
                *(uint32_t*)(tile + i * 4096 + d * 1024 + ldsQ) = wrd;
            }
        }
        __syncthreads();
        {   // tile is byte-identical to global span [mb32<<19 | kw<<14 .. +16KB)
            const int4* s = (const int4*)tile;
            int4* dst = (int4*)(dstBase + ((size_t)kw << 14));
#pragma unroll
            for (int q = 0; q < 4; ++q) dst[t + 256 * q] = s[t + 256 * q];
        }
        __syncthreads();
    }
}

// ---------------- fallback: R1 planar in-place pack ------------------------
__global__ void pack_x_kernel(float* __restrict__ x) {
    const int b = blockIdx.x, t = threadIdx.x;
    float* row = x + (size_t)b * DIM;
    float f[16];
#pragma unroll
    for (int i = 0; i < 4; ++i) {
        float4 v = ((const float4*)(row + t * 16))[i];
        f[i*4+0] = v.x; f[i*4+1] = v.y; f[i*4+2] = v.z; f[i*4+3] = v.w;
    }
    __syncthreads();
    uint32_t wds[4][4];
#pragma unroll
    for (int j = 0; j < 4; ++j) {
#pragma unroll
        for (int d = 0; d < 4; ++d) wds[d][j] = 0u;
#pragma unroll
        for (int i = 0; i < 4; ++i) {
            int v = __float2int_rn(f[j*4+i] * 67108864.0f);
#pragma unroll
            for (int d = 0; d < 4; ++d) {
                int bb = (int)(int8_t)(v & 0xff);
                wds[d][j] |= (uint32_t)(bb & 0xff) << (8 * i);
                v = (v - bb) >> 8;
            }
        }
    }
    int8_t* rowb = (int8_t*)row;
#pragma unroll
    for (int d = 0; d < 4; ++d) {
        int4 o; o.x = (int)wds[d][0]; o.y = (int)wds[d][1];
        o.z = (int)wds[d][2]; o.w = (int)wds[d][3];
        *(int4*)(rowb + d * DIM + t * 16) = o;
    }
}

// ---------------- pack W1 signs into MFMA-fragment-ordered blocks ----------
__global__ void pack_w1_kernel(const float* __restrict__ W1, int8_t* __restrict__ wsB) {
    const int tg = blockIdx.x * 256 + threadIdx.x;
    const int n  = tg >> 8;
    const int k0 = (tg & 255) << 4;
    const float* src = W1 + (size_t)n * DIM + k0;
    uint32_t w[4];
#pragma unroll
    for (int j = 0; j < 4; ++j) {
        float4 v = ((const float4*)src)[j];
        uint32_t b0 = (v.x >= 0.f) ? 0x01u : 0xFFu;
        uint32_t b1 = (v.y >= 0.f) ? 0x01u : 0xFFu;
        uint32_t b2 = (v.z >= 0.f) ? 0x01u : 0xFFu;
        uint32_t b3 = (v.w >= 0.f) ? 0x01u : 0xFFu;
        w[j] = b0 | (b1 << 8) | (b2 << 16) | (b3 << 24);
    }
    const int nb = n >> 7, kt = k0 >> 6;
    const int nsub = (n >> 5) & 3, ks = (k0 >> 5) & 1;
    const int L = (n & 31) | (((k0 >> 4) & 1) << 5);
    const size_t off = ((size_t)(nb * 64 + kt) << 13) + (nsub << 11) + (ks << 10) + (L << 4);
    int4 o; o.x = (int)w[0]; o.y = (int)w[1]; o.z = (int)w[2]; o.w = (int)w[3];
    *(int4*)(wsB + off) = o;
}

__global__ void pack_w2_kernel(const float* __restrict__ W2, int8_t* __restrict__ w2s) {
    const int j = blockIdx.x * 256 + threadIdx.x;
    if (j < DIM) w2s[j] = (W2[j] >= 0.f) ? (int8_t)1 : (int8_t)-1;
}

// ---------------- R5 GEMM: A->regs (2-deep), B->LDS (3-deep) ---------------
// Per stage per wave: 8 global_load_dwordx4 (A, next stage), 2 dma16 (B,
// stage+2), 4 ds_read_b128 (B frags), 16 MFMA. Issue order A-then-B makes
// the barrier wait a constant vmcnt(2): only the newest B-DMA pair stays
// outstanding; A(kt) and B(kt) are guaranteed landed.
#define STGB 8192

#define PIPE_BARRIER(N) do {                                               \
    __builtin_amdgcn_sched_barrier(0);                                     \
    asm volatile("s_waitcnt vmcnt(" #N ") lgkmcnt(0)" ::: "memory");       \
    __builtin_amdgcn_s_barrier();                                          \
    __builtin_amdgcn_sched_barrier(0);                                     \
} while (0)

// A fragments: global stream is already MFMA-fragment-ordered.
#define LOAD_AF(dst, kt_) do {                                             \
    const int8_t* _p = gA + ((size_t)(kt_) << 13);                         \
    _Pragma("unroll") for (int _s = 0; _s < 2; ++_s)                       \
    _Pragma("unroll") for (int _d = 0; _d < 4; ++_d)                       \
        dst[_s * 4 + _d] = *(const v4i*)(_p + (_s << 12) + (_d << 10));    \
} while (0)

// B chunk (nsub=w, ks=0..1) -> LDS buffer ib at (w<<11)
#define DMA_B(kt_, ib) do {                                                \
    const int8_t* _s = gB + ((size_t)(kt_) << 13);                         \
    int8_t* _dst = &stg[ib][w << 11];                                      \
    dma16(_s, _dst); dma16(_s + 1024, _dst + 1024);                        \
} while (0)

#define MFMA_STAGE(af_, cb) do {                                           \
    const int8_t* _bb = &stg[cb][(wx << 12) + (lane << 4)];                \
    v4i _bf[2][2];                                                         \
    _Pragma("unroll") for (int _s = 0; _s < 2; ++_s)                       \
    _Pragma("unroll") for (int _n = 0; _n < 2; ++_n)                       \
        _bf[_s][_n] = *(const v4i*)(_bb + (_n << 11) + (_s << 10));        \
    _Pragma("unroll") for (int _s = 0; _s < 2; ++_s)                       \
    _Pragma("unroll") for (int _n = 0; _n < 2; ++_n)                       \
    _Pragma("unroll") for (int _d = 0; _d < 4; ++_d)                       \
        acc[_n][_d] = __builtin_amdgcn_mfma_i32_32x32x32_i8(               \
            af_[_s * 4 + _d], _bf[_s][_n], acc[_n][_d], 0, 0, 0);          \
} while (0)

// One stage: wait(A(kt),B(kt)); issue A(kt+1)->ia_reg, B(kt+2)->LDS[ib];
// compute with ca_reg + LDS[cb].
#define STEP(kt_, ca_reg, cb, ia_reg, ib) do {                             \
    PIPE_BARRIER(2);                                                       \
    LOAD_AF(ia_reg, (kt_) + 1);                                            \
    DMA_B((kt_) + 2, ib);                                                  \
    __builtin_amdgcn_sched_barrier(0);                                     \
    MFMA_STAGE(ca_reg, cb);                                                \
} while (0)

__launch_bounds__(256, 2)
__global__ void gemm_direct_kernel(const int8_t* __restrict__ wsA,
                                   const int8_t* __restrict__ wsB,
                                   const int8_t* __restrict__ w2s,
                                   int* __restrict__ logit) {
    __shared__ __align__(16) int8_t stg[3][STGB];   // 24 KB (B only)

    const int bid = blockIdx.x;
    const int nb = bid & 31, mb = bid >> 5;   // nb fastest: A window shared in L2
    const int t = threadIdx.x, lane = t & 63, w = t >> 6;
    const int wy = w >> 1, wx = w & 1;        // wave tile: 32(m) x 64(n)

    v16i acc[2][4];
#pragma unroll
    for (int n = 0; n < 2; ++n)
#pragma unroll
        for (int d = 0; d < 4; ++d)
#pragma unroll
            for (int i = 0; i < 16; ++i) acc[n][d][i] = 0;

    const int8_t* gA = wsA + ((size_t)(mb * 2 + wy) << 19) + (lane << 4);
    const int8_t* gB = wsB + ((size_t)(nb * 64) << 13) + (w << 11) + (lane << 4);

    v4i afA[8], afB[8];
    // prologue: in-flight order must be [B(0), A(0), B(1)] so the first
    // steady-state wait vmcnt(2) leaves exactly B(1) outstanding.
    DMA_B(0, 0);
    LOAD_AF(afA, 0);
    DMA_B(1, 1);

    // 64 stages; A ping-pong (mod 2) x B triple-buffer (mod 3) -> period 6.
#pragma unroll 1
    for (int kt = 0; kt < 60; kt += 6) {
        STEP(kt + 0, afA, 0, afB, 2);
        STEP(kt + 1, afB, 1, afA, 0);
        STEP(kt + 2, afA, 2, afB, 1);
        STEP(kt + 3, afB, 0, afA, 2);
        STEP(kt + 4, afA, 1, afB, 0);
        STEP(kt + 5, afB, 2, afA, 1);
    }
    STEP(60, afA, 0, afB, 2);     // issues A(61), B(62)
    STEP(61, afB, 1, afA, 0);     // issues A(62), B(63)
    // kt=62: no B(64); still vmcnt(2) (leaves B(63) pair outstanding)
    PIPE_BARRIER(2);
    LOAD_AF(afB, 63);
    __builtin_amdgcn_sched_barrier(0);
    MFMA_STAGE(afA, 2);
    // kt=63: final drain
    PIPE_BARRIER(0);
    MFMA_STAGE(afB, 0);

    // epilogue: recombine digits -> exact sign -> *sign(W2) -> row sums -> atomic
    const int half = lane >> 5, col = lane & 31;
    int psum[16];
#pragma unroll
    for (int r = 0; r < 16; ++r) psum[r] = 0;
#pragma unroll
    for (int n = 0; n < 2; ++n) {
        const int j = nb * NT + wx * 64 + n * 32 + col;
        const int w2v = (int)w2s[j];
#pragma unroll
        for (int r = 0; r < 16; ++r) {
            long long h = (long long)acc[n][0][r]
                        + ((long long)acc[n][1][r] << 8)
                        + ((long long)acc[n][2][r] << 16)
                        + ((long long)acc[n][3][r] << 24);
            psum[r] += (h >= 0) ? w2v : -w2v;
        }
    }
#pragma unroll
    for (int r = 0; r < 16; ++r) {
#pragma unroll
        for (int m = 1; m <= 16; m <<= 1)
            psum[r] += __shfl_xor(psum[r], m, 64);
    }
    if (col == 0) {
        const int rowBase = mb * MT + wy * 32 + 4 * half;
#pragma unroll
        for (int r = 0; r < 16; ++r)
            atomicAdd(logit + rowBase + (r & 3) + 8 * (r >> 2), psum[r]);
    }
}

// ---------------- fallback: R1 GEMM (A planar through LDS) -----------------
__launch_bounds__(256, 2)
__global__ void gemm_kernel(const int8_t* __restrict__ xq,
                            const int8_t* __restrict__ wsB,
                            const int8_t* __restrict__ w2s,
                            int* __restrict__ logit) {
    __shared__ __align__(16) int8_t aT[4 * MT * KT];
    __shared__ __align__(16) int8_t bT[NT * KT];

    const int bid = blockIdx.x;
    const int nb = bid & 31, mb = bid >> 5;
    const int t = threadIdx.x, lane = t & 63, w = t >> 6;
    const int wy = w >> 1, wx = w & 1;

    v16i acc[2][4];
#pragma unroll
    for (int n = 0; n < 2; ++n)
#pragma unroll
        for (int d = 0; d < 4; ++d)
#pragma unroll
            for (int i = 0; i < 16; ++i) acc[n][d][i] = 0;

    const int8_t* aSrc = xq + (size_t)(mb * MT + lane) * (4 * DIM) + w * DIM;
    const int8_t* bSrc = wsB + ((size_t)(nb * 64) << 13) + t * 32;
    const int aDst = w * (MT * KT) + ((lane >> 5) << 11) + ((lane & 31) << 4);

    for (int kt = 0; kt < DIM / KT; ++kt) {
#pragma unroll
        for (int k16 = 0; k16 < 4; ++k16) {
            v4i v = *(const v4i*)(aSrc + kt * KT + k16 * 16);
            *(v4i*)(aT + aDst + ((k16 >> 1) << 10) + ((k16 & 1) << 9)) = v;
        }
        {
            const v4i* s = (const v4i*)(bSrc + ((size_t)kt << 13));
            *(v4i*)(bT + t * 32)      = s[0];
            *(v4i*)(bT + t * 32 + 16) = s[1];
        }
        __syncthreads();
#pragma unroll
        for (int s = 0; s < 2; ++s) {
            v4i af[4], bf[2];
#pragma unroll
            for (int d = 0; d < 4; ++d)
                af[d] = *(const v4i*)(aT + d * (MT * KT) + (wy << 11) + (s << 10) + (lane << 4));
#pragma unroll
            for (int n = 0; n < 2; ++n)
                bf[n] = *(const v4i*)(bT + ((wx * 2 + n) << 11) + (s << 10) + (lane << 4));
#pragma unroll
            for (int n = 0; n < 2; ++n)
#pragma unroll
                for (int d = 0; d < 4; ++d)
                    acc[n][d] = __builtin_amdgcn_mfma_i32_32x32x32_i8(af[d], bf[n], acc[n][d], 0, 0, 0);
        }
        __syncthreads();
    }

    const int half = lane >> 5, col = lane & 31;
    int psum[16];
#pragma unroll
    for (int r = 0; r < 16; ++r) psum[r] = 0;
#pragma unroll
    for (int n = 0; n < 2; ++n) {
        const int j = nb * NT + wx * 64 + n * 32 + col;
        const int w2v = (int)w2s[j];
#pragma unroll
        for (int r = 0; r < 16; ++r) {
            long long h = (long long)acc[n][0][r]
                        + ((long long)acc[n][1][r] << 8)
                        + ((long long)acc[n][2][r] << 16)
                        + ((long long)acc[n][3][r] << 24);
            psum[r] += (h >= 0) ? w2v : -w2v;
        }
    }
#pragma unroll
    for (int r = 0; r < 16; ++r) {
#pragma unroll
        for (int m = 1; m <= 16; m <<= 1)
            psum[r] += __shfl_xor(psum[r], m, 64);
    }
    if (col == 0) {
        const int rowBase = mb * MT + wy * 32 + 4 * half;
#pragma unroll
        for (int r = 0; r < 16; ++r)
            atomicAdd(logit + rowBase + (r & 3) + 8 * (r >> 2), psum[r]);
    }
}

// ---------------- finalize: sigmoid + threshold ----------------------------
__global__ void finalize_kernel(const int* __restrict__ logit, float* __restrict__ out) {
    const int b = blockIdx.x * 256 + threadIdx.x;
    if (b < B_ROWS) {
        const int l = logit[b];
        out[b]          = 1.f / (1.f + expf(-(float)l));
        out[B_ROWS + b] = (l >= 0) ? 1.f : 0.f;
    }
}

extern "C" void kernel_launch(void* const* d_in, const int* in_sizes, int n_in,
                              void* d_out, int out_size, void* d_ws, size_t ws_size,
                              hipStream_t stream) {
    float*       x   = (float*)d_in[0];
    const float* W1  = (const float*)d_in[1];
    const float* W2  = (const float*)d_in[2];
    float*       out = (float*)d_out;

    int8_t* ws    = (int8_t*)d_ws;
    int*    logit = (int*)(ws + WS_LOGIT);
    int8_t* w2s   = ws + WS_W2S;
    int8_t* wsB   = ws + WS_B;

    hipMemsetAsync(logit, 0, B_ROWS * sizeof(int), stream);
    pack_w1_kernel<<<DIM, 256, 0, stream>>>(W1, wsB);
    pack_w2_kernel<<<16, 256, 0, stream>>>(W2, w2s);

    if (ws_size >= WS_NEEDED) {
        int8_t* wsA = ws + WS_A;
        pack_x_frag_kernel<<<B_ROWS / 32, 256, 0, stream>>>(x, wsA);
        gemm_direct_kernel<<<(B_ROWS / MT) * (DIM / NT), 256, 0, stream>>>(wsA, wsB, w2s, logit);
    } else {
        pack_x_kernel<<<B_ROWS, 256, 0, stream>>>(x);
        gemm_kernel<<<(B_ROWS / MT) * (DIM / NT), 256, 0, stream>>>((const int8_t*)x, wsB, w2s, logit);
    }
    finalize_kernel<<<B_ROWS / 256, 256, 0, stream>>>(logit, out);
}

// Round 3
// 1553.901 us; speedup vs baseline: 1.0856x; 1.0856x over previous
//
#include <hip/hip_runtime.h>
#include <stdint.h>

// Binary-weight MLP forward, exact int8 digit-plane formulation.
// R6: asymmetric operand split. A digit-planes (16 KB/stage) stream
// global->LDS via global_load_lds, 3-deep; B signs (4 KB/stage/wave) stream
// global->VGPR, 3 register sets, loaded 2 stages ahead. Constant
// s_waitcnt vmcnt(8) per barrier (next stage's 4 B-loads + 4 A-DMAs stay in
// flight). LDS traffic drops to 96 KB/CU-stage (857 cyc < 1170 cyc MFMA);
// L2 traffic 32 KB/CU-stage (27 B/cyc < 56 ceiling): both pipes off the
// critical path. s_setprio(1) wraps the ds_read+MFMA cluster (T5).

typedef int v4i  __attribute__((ext_vector_type(4)));
typedef int v16i __attribute__((ext_vector_type(16)));

#define B_ROWS   16384
#define DIM      4096
#define MT       64      // block m-tile
#define NT       128     // block n-tile
#define KT       64      // k-tile (pipeline stage)

#define WS_LOGIT  0
#define WS_W2S    65536
#define WS_B      69632
#define WS_A      (69632 + 16777216)
#define WS_NEEDED ((size_t)WS_A + 268435456ULL)

__device__ __forceinline__ void dma16(const void* g, void* l) {
    __builtin_amdgcn_global_load_lds(
        (const __attribute__((address_space(1))) void*)g,
        (__attribute__((address_space(3))) void*)l, 16, 0, 0);
}

// ---------------- pack x -> fragment-ordered digit planes in wsA -----------
// Global layout: offA(m,k,d) = (m>>5)<<19 | (k>>5)<<12 | d<<10 | L<<4 | (k&15)
//   with L = ((k>>4)&1)*32 + (m&31)  (== MFMA A-operand lane index).
__global__ void pack_x_frag_kernel(const float* __restrict__ x, int8_t* __restrict__ wsA) {
    __shared__ __align__(16) int8_t tile[16384];
    const int mb32 = blockIdx.x, t = threadIdx.x;
    const int r = t >> 3;          // row within 32-row group
    const int c = t & 7;           // float4-column subgroup
    const int kh = (c >> 2) & 1;   // (k>>4)&1 for this thread's elements
    const int L = kh * 32 + r;
    const int ldsQ = L * 16 + (c & 3) * 4;   // + i*4096 + d*1024
    const float* srcRow = x + ((size_t)(mb32 * 32 + r) << 12);
    int8_t* dstBase = wsA + ((size_t)mb32 << 19);

    for (int kw = 0; kw < 32; ++kw) {
#pragma unroll
        for (int i = 0; i < 4; ++i) {
            const int j = c + 8 * i;                       // float4 index in window
            float4 f = ((const float4*)(srcRow + (kw << 7)))[j];
            float fv[4] = {f.x, f.y, f.z, f.w};
            int dig[4][4];                                  // [elem][digit]
#pragma unroll
            for (int e = 0; e < 4; ++e) {
                int v = __float2int_rn(fv[e] * 67108864.0f); // * 2^26, exact
#pragma unroll
                for (int d = 0; d < 4; ++d) {
                    int b = (int)(int8_t)(v & 0xff);
                    dig[e][d] = b & 0xff;
                    v = (v - b) >> 8;                        // exact
                }
            }
#pragma unroll
            for (int d = 0; d < 4; ++d) {
                uint32_t wrd = (uint32_t)dig[0][d] | ((uint32_t)dig[1][d] << 8)
                             | ((uint32_t)dig[2][d] << 16) | ((uint32_t)dig[3][d] << 24);
                *(uint32_t*)(tile + i * 4096 + d * 1024 + ldsQ) = wrd;
            }
        }
        __syncthreads();
        {   // tile is byte-identical to global span [mb32<<19 | kw<<14 .. +16KB)
            const int4* s = (const int4*)tile;
            int4* dst = (int4*)(dstBase + ((size_t)kw << 14));
#pragma unroll
            for (int q = 0; q < 4; ++q) dst[t + 256 * q] = s[t + 256 * q];
        }
        __syncthreads();
    }
}

// ---------------- fallback: R1 planar in-place pack ------------------------
__global__ void pack_x_kernel(float* __restrict__ x) {
    const int b = blockIdx.x, t = threadIdx.x;
    float* row = x + (size_t)b * DIM;
    float f[16];
#pragma unroll
    for (int i = 0; i < 4; ++i) {
        float4 v = ((const float4*)(row + t * 16))[i];
        f[i*4+0] = v.x; f[i*4+1] = v.y; f[i*4+2] = v.z; f[i*4+3] = v.w;
    }
    __syncthreads();
    uint32_t wds[4][4];
#pragma unroll
    for (int j = 0; j < 4; ++j) {
#pragma unroll
        for (int d = 0; d < 4; ++d) wds[d][j] = 0u;
#pragma unroll
        for (int i = 0; i < 4; ++i) {
            int v = __float2int_rn(f[j*4+i] * 67108864.0f);
#pragma unroll
            for (int d = 0; d < 4; ++d) {
                int bb = (int)(int8_t)(v & 0xff);
                wds[d][j] |= (uint32_t)(bb & 0xff) << (8 * i);
                v = (v - bb) >> 8;
            }
        }
    }
    int8_t* rowb = (int8_t*)row;
#pragma unroll
    for (int d = 0; d < 4; ++d) {
        int4 o; o.x = (int)wds[d][0]; o.y = (int)wds[d][1];
        o.z = (int)wds[d][2]; o.w = (int)wds[d][3];
        *(int4*)(rowb + d * DIM + t * 16) = o;
    }
}

// ---------------- pack W1 signs into MFMA-fragment-ordered blocks ----------
__global__ void pack_w1_kernel(const float* __restrict__ W1, int8_t* __restrict__ wsB) {
    const int tg = blockIdx.x * 256 + threadIdx.x;
    const int n  = tg >> 8;
    const int k0 = (tg & 255) << 4;
    const float* src = W1 + (size_t)n * DIM + k0;
    uint32_t w[4];
#pragma unroll
    for (int j = 0; j < 4; ++j) {
        float4 v = ((const float4*)src)[j];
        uint32_t b0 = (v.x >= 0.f) ? 0x01u : 0xFFu;
        uint32_t b1 = (v.y >= 0.f) ? 0x01u : 0xFFu;
        uint32_t b2 = (v.z >= 0.f) ? 0x01u : 0xFFu;
        uint32_t b3 = (v.w >= 0.f) ? 0x01u : 0xFFu;
        w[j] = b0 | (b1 << 8) | (b2 << 16) | (b3 << 24);
    }
    const int nb = n >> 7, kt = k0 >> 6;
    const int nsub = (n >> 5) & 3, ks = (k0 >> 5) & 1;
    const int L = (n & 31) | (((k0 >> 4) & 1) << 5);
    const size_t off = ((size_t)(nb * 64 + kt) << 13) + (nsub << 11) + (ks << 10) + (L << 4);
    int4 o; o.x = (int)w[0]; o.y = (int)w[1]; o.z = (int)w[2]; o.w = (int)w[3];
    *(int4*)(wsB + off) = o;
}

__global__ void pack_w2_kernel(const float* __restrict__ W2, int8_t* __restrict__ w2s) {
    const int j = blockIdx.x * 256 + threadIdx.x;
    if (j < DIM) w2s[j] = (W2[j] >= 0.f) ? (int8_t)1 : (int8_t)-1;
}

// ---------------- R6 GEMM: A->LDS (3-deep DMA), B->regs (3 sets) -----------
#define STGB 16384

#define PIPE_BARRIER(N) do {                                               \
    __builtin_amdgcn_sched_barrier(0);                                     \
    asm volatile("s_waitcnt vmcnt(" #N ") lgkmcnt(0)" ::: "memory");       \
    __builtin_amdgcn_s_barrier();                                          \
    __builtin_amdgcn_sched_barrier(0);                                     \
} while (0)

// B fragments (wave wx): bf[s][n] <- wsB chunk (nsub=wx*2+n, ks=s), 4 loads.
#define LOAD_BF(dst, kt_) do {                                             \
    const int8_t* _p = gBr + ((size_t)(kt_) << 13);                        \
    _Pragma("unroll") for (int _s = 0; _s < 2; ++_s)                       \
    _Pragma("unroll") for (int _n = 0; _n < 2; ++_n)                       \
        dst[_s][_n] = *(const v4i*)(_p + (_n << 11) + (_s << 10));         \
} while (0)

// A chunk group (wy=w>>1, ks=w&1, d=0..3) -> LDS buffer ib, 4 dma16.
#define DMA_A(kt_, ib) do {                                                \
    const int8_t* _s = gA + ((size_t)(kt_) << 13);                         \
    int8_t* _dst = &stg[ib][w << 12];                                      \
    dma16(_s,        _dst);                                                \
    dma16(_s + 1024, _dst + 1024);                                         \
    dma16(_s + 2048, _dst + 2048);                                         \
    dma16(_s + 3072, _dst + 3072);                                         \
} while (0)

// Compute one stage: 8 ds_read_b128 (A frags) + 16 MFMA, B already in regs.
#define MFMA_STAGE(cb, bf_) do {                                           \
    const int8_t* _ab = &stg[cb][(wy << 13) + (lane << 4)];                \
    v4i _af[2][4];                                                         \
    _Pragma("unroll") for (int _s = 0; _s < 2; ++_s)                       \
    _Pragma("unroll") for (int _d = 0; _d < 4; ++_d)                       \
        _af[_s][_d] = *(const v4i*)(_ab + (_s << 12) + (_d << 10));        \
    __builtin_amdgcn_s_setprio(1);                                         \
    _Pragma("unroll") for (int _s = 0; _s < 2; ++_s)                       \
    _Pragma("unroll") for (int _n = 0; _n < 2; ++_n)                       \
    _Pragma("unroll") for (int _d = 0; _d < 4; ++_d)                       \
        acc[_n][_d] = __builtin_amdgcn_mfma_i32_32x32x32_i8(               \
            _af[_s][_d], bf_[_s][_n], acc[_n][_d], 0, 0, 0);               \
    __builtin_amdgcn_s_setprio(0);                                         \
} while (0)

// One stage: wait(A(kt) in LDS, B(kt) in regs); issue B(kt+2)->bfi,
// A(kt+2)->LDS[ib]; compute with LDS[cb] + bfc.
#define STEP(kt_, cb, bfc, bfi, ib) do {                                   \
    PIPE_BARRIER(8);                                                       \
    LOAD_BF(bfi, (kt_) + 2);                                               \
    DMA_A((kt_) + 2, ib);                                                  \
    __builtin_amdgcn_sched_barrier(0);                                     \
    MFMA_STAGE(cb, bfc);                                                   \
} while (0)

__launch_bounds__(256, 2)
__global__ void gemm_direct_kernel(const int8_t* __restrict__ wsA,
                                   const int8_t* __restrict__ wsB,
                                   const int8_t* __restrict__ w2s,
                                   int* __restrict__ logit) {
    __shared__ __align__(16) int8_t stg[3][STGB];   // 48 KB (A only)

    const int bid = blockIdx.x;
    const int nb = bid & 31, mb = bid >> 5;   // nb fastest: A window shared in L2
    const int t = threadIdx.x, lane = t & 63, w = t >> 6;
    const int wy = w >> 1, wx = w & 1;        // wave tile: 32(m) x 64(n)

    v16i acc[2][4];
#pragma unroll
    for (int n = 0; n < 2; ++n)
#pragma unroll
        for (int d = 0; d < 4; ++d)
#pragma unroll
            for (int i = 0; i < 16; ++i) acc[n][d][i] = 0;

    // A: wave w stages chunk group (wy=w>>1, ks=w&1, d=0..3)
    const int8_t* gA  = wsA + ((size_t)(mb * 2 + wy) << 19) + ((size_t)wx << 12) + (lane << 4);
    // wait: ks for A staging is w&1; reuse wx (== w&1) to avoid extra reg
    // B: per-wave fragment base (nsub = wx*2 + n), per-lane address
    const int8_t* gBr = wsB + ((size_t)(nb * 64) << 13) + ((size_t)wx << 12) + (lane << 4);

    v4i bf0[2][2], bf1[2][2], bf2[2][2];
    // prologue vmem order: [B(0)x4, A(0)x4, B(1)x4, A(1)x4] so the steady
    // vmcnt(8) leaves exactly stage kt+1's 8 ops outstanding.
    LOAD_BF(bf0, 0);
    DMA_A(0, 0);
    LOAD_BF(bf1, 1);
    DMA_A(1, 1);

    // 64 stages, period-3 unroll (LDS buf and B reg set both mod 3).
#pragma unroll 1
    for (int kt = 0; kt < 60; kt += 3) {
        STEP(kt + 0, 0, bf0, bf2, 2);
        STEP(kt + 1, 1, bf1, bf0, 0);
        STEP(kt + 2, 2, bf2, bf1, 1);
    }
    STEP(60, 0, bf0, bf2, 2);     // issues B(62)->bf2, A(62)->buf2
    STEP(61, 1, bf1, bf0, 0);     // issues B(63)->bf0, A(63)->buf0
    PIPE_BARRIER(8);              // stage 62 landed (63's 8 ops in flight)
    MFMA_STAGE(2, bf2);
    PIPE_BARRIER(0);              // final drain: stage 63 landed
    MFMA_STAGE(0, bf0);

    // epilogue: recombine digits -> exact sign -> *sign(W2) -> row sums -> atomic
    const int half = lane >> 5, col = lane & 31;
    int psum[16];
#pragma unroll
    for (int r = 0; r < 16; ++r) psum[r] = 0;
#pragma unroll
    for (int n = 0; n < 2; ++n) {
        const int j = nb * NT + wx * 64 + n * 32 + col;
        const int w2v = (int)w2s[j];
#pragma unroll
        for (int r = 0; r < 16; ++r) {
            long long h = (long long)acc[n][0][r]
                        + ((long long)acc[n][1][r] << 8)
                        + ((long long)acc[n][2][r] << 16)
                        + ((long long)acc[n][3][r] << 24);
            psum[r] += (h >= 0) ? w2v : -w2v;
        }
    }
#pragma unroll
    for (int r = 0; r < 16; ++r) {
#pragma unroll
        for (int m = 1; m <= 16; m <<= 1)
            psum[r] += __shfl_xor(psum[r], m, 64);
    }
    if (col == 0) {
        const int rowBase = mb * MT + wy * 32 + 4 * half;
#pragma unroll
        for (int r = 0; r < 16; ++r)
            atomicAdd(logit + rowBase + (r & 3) + 8 * (r >> 2), psum[r]);
    }
}

// ---------------- fallback: R1 GEMM (A planar through LDS) -----------------
__launch_bounds__(256, 2)
__global__ void gemm_kernel(const int8_t* __restrict__ xq,
                            const int8_t* __restrict__ wsB,
                            const int8_t* __restrict__ w2s,
                            int* __restrict__ logit) {
    __shared__ __align__(16) int8_t aT[4 * MT * KT];
    __shared__ __align__(16) int8_t bT[NT * KT];

    const int bid = blockIdx.x;
    const int nb = bid & 31, mb = bid >> 5;
    const int t = threadIdx.x, lane = t & 63, w = t >> 6;
    const int wy = w >> 1, wx = w & 1;

    v16i acc[2][4];
#pragma unroll
    for (int n = 0; n < 2; ++n)
#pragma unroll
        for (int d = 0; d < 4; ++d)
#pragma unroll
            for (int i = 0; i < 16; ++i) acc[n][d][i] = 0;

    const int8_t* aSrc = xq + (size_t)(mb * MT + lane) * (4 * DIM) + w * DIM;
    const int8_t* bSrc = wsB + ((size_t)(nb * 64) << 13) + t * 32;
    const int aDst = w * (MT * KT) + ((lane >> 5) << 11) + ((lane & 31) << 4);

    for (int kt = 0; kt < DIM / KT; ++kt) {
#pragma unroll
        for (int k16 = 0; k16 < 4; ++k16) {
            v4i v = *(const v4i*)(aSrc + kt * KT + k16 * 16);
            *(v4i*)(aT + aDst + ((k16 >> 1) << 10) + ((k16 & 1) << 9)) = v;
        }
        {
            const v4i* s = (const v4i*)(bSrc + ((size_t)kt << 13));
            *(v4i*)(bT + t * 32)      = s[0];
            *(v4i*)(bT + t * 32 + 16) = s[1];
        }
        __syncthreads();
#pragma unroll
        for (int s = 0; s < 2; ++s) {
            v4i af[4], bf[2];
#pragma unroll
            for (int d = 0; d < 4; ++d)
                af[d] = *(const v4i*)(aT + d * (MT * KT) + (wy << 11) + (s << 10) + (lane << 4));
#pragma unroll
            for (int n = 0; n < 2; ++n)
                bf[n] = *(const v4i*)(bT + ((wx * 2 + n) << 11) + (s << 10) + (lane << 4));
#pragma unroll
            for (int n = 0; n < 2; ++n)
#pragma unroll
                for (int d = 0; d < 4; ++d)
                    acc[n][d] = __builtin_amdgcn_mfma_i32_32x32x32_i8(af[d], bf[n], acc[n][d], 0, 0, 0);
        }
        __syncthreads();
    }

    const int half = lane >> 5, col = lane & 31;
    int psum[16];
#pragma unroll
    for (int r = 0; r < 16; ++r) psum[r] = 0;
#pragma unroll
    for (int n = 0; n < 2; ++n) {
        const int j = nb * NT + wx * 64 + n * 32 + col;
        const int w2v = (int)w2s[j];
#pragma unroll
        for (int r = 0; r < 16; ++r) {
            long long h = (long long)acc[n][0][r]
                        + ((long long)acc[n][1][r] << 8)
                        + ((long long)acc[n][2][r] << 16)
                        + ((long long)acc[n][3][r] << 24);
            psum[r] += (h >= 0) ? w2v : -w2v;
        }
    }
#pragma unroll
    for (int r = 0; r < 16; ++r) {
#pragma unroll
        for (int m = 1; m <= 16; m <<= 1)
            psum[r] += __shfl_xor(psum[r], m, 64);
    }
    if (col == 0) {
        const int rowBase = mb * MT + wy * 32 + 4 * half;
#pragma unroll
        for (int r = 0; r < 16; ++r)
            atomicAdd(logit + rowBase + (r & 3) + 8 * (r >> 2), psum[r]);
    }
}

// ---------------- finalize: sigmoid + threshold ----------------------------
__global__ void finalize_kernel(const int* __restrict__ logit, float* __restrict__ out) {
    const int b = blockIdx.x * 256 + threadIdx.x;
    if (b < B_ROWS) {
        const int l = logit[b];
        out[b]          = 1.f / (1.f + expf(-(float)l));
        out[B_ROWS + b] = (l >= 0) ? 1.f : 0.f;
    }
}

extern "C" void kernel_launch(void* const* d_in, const int* in_sizes, int n_in,
                              void* d_out, int out_size, void* d_ws, size_t ws_size,
                              hipStream_t stream) {
    float*       x   = (float*)d_in[0];
    const float* W1  = (const float*)d_in[1];
    const float* W2  = (const float*)d_in[2];
    float*       out = (float*)d_out;

    int8_t* ws    = (int8_t*)d_ws;
    int*    logit = (int*)(ws + WS_LOGIT);
    int8_t* w2s   = ws + WS_W2S;
    int8_t* wsB   = ws + WS_B;

    hipMemsetAsync(logit, 0, B_ROWS * sizeof(int), stream);
    pack_w1_kernel<<<DIM, 256, 0, stream>>>(W1, wsB);
    pack_w2_kernel<<<16, 256, 0, stream>>>(W2, w2s);

    if (ws_size >= WS_NEEDED) {
        int8_t* wsA = ws + WS_A;
        pack_x_frag_kernel<<<B_ROWS / 32, 256, 0, stream>>>(x, wsA);
        gemm_direct_kernel<<<(B_ROWS / MT) * (DIM / NT), 256, 0, stream>>>(wsA, wsB, w2s, logit);
    } else {
        pack_x_kernel<<<B_ROWS, 256, 0, stream>>>(x);
        gemm_kernel<<<(B_ROWS / MT) * (DIM / NT), 256, 0, stream>>>((const int8_t*)x, wsB, w2s, logit);
    }
    finalize_kernel<<<B_ROWS / 256, 256, 0, stream>>>(logit, out);
}